// Round 4
// baseline (409.820 us; speedup 1.0000x reference)
//
#include <hip/hip_runtime.h>
#include <cstdint>
#include <cstddef>

#define ALPHA 0.2f
#define NEG_INF -1e30f

constexpr int B = 4, N = 512, IN_F = 256, E_F = 64, OUT_F = 256;

// ---------------------------------------------------------------------------
// K1: h = x @ W (4 rows/block, 512 blocks), fused s_i/s_j.
//     Extra block (blockIdx.x == 512) computes w1a3 = W1 @ a3.
// ---------------------------------------------------------------------------
__global__ __launch_bounds__(256) void k_h(const float* __restrict__ x,
                                           const float* __restrict__ W,
                                           const float* __restrict__ W1,
                                           const float* __restrict__ a,
                                           float* __restrict__ h,
                                           float* __restrict__ s_i,
                                           float* __restrict__ s_j,
                                           float* __restrict__ w1a3) {
    int tid = threadIdx.x;
    if (blockIdx.x == (B * N) / 4) {
        int e = tid >> 2, part = tid & 3;
        const float* row = W1 + (size_t)e * OUT_F + part * 64;
        const float* a3 = a + 2 * OUT_F + part * 64;
        float s = 0.f;
        #pragma unroll 8
        for (int o = 0; o < 64; ++o) s += row[o] * a3[o];
        s += __shfl_xor(s, 1);
        s += __shfl_xor(s, 2);
        if (part == 0) w1a3[e] = s;
        return;
    }
    int wv = tid >> 6, lane = tid & 63;
    int row = blockIdx.x * 4 + wv;     // each wave owns one row
    int c4 = lane * 4;

    __shared__ float xs[4][IN_F];
    *(float4*)&xs[wv][c4] = *(const float4*)&x[(size_t)row * IN_F + c4];
    __syncthreads();

    float4 acc = {0.f, 0.f, 0.f, 0.f};
    for (int k = 0; k < IN_F; ++k) {
        float4 w4 = *(const float4*)&W[(size_t)k * OUT_F + c4];
        float xv = xs[wv][k];
        acc.x = fmaf(xv, w4.x, acc.x);
        acc.y = fmaf(xv, w4.y, acc.y);
        acc.z = fmaf(xv, w4.z, acc.z);
        acc.w = fmaf(xv, w4.w, acc.w);
    }
    *(float4*)&h[(size_t)row * OUT_F + c4] = acc;

    float4 a1v = *(const float4*)&a[c4];
    float4 a2v = *(const float4*)&a[OUT_F + c4];
    float p1 = acc.x * a1v.x + acc.y * a1v.y + acc.z * a1v.z + acc.w * a1v.w;
    float p2 = acc.x * a2v.x + acc.y * a2v.y + acc.z * a2v.z + acc.w * a2v.w;
    #pragma unroll
    for (int off = 32; off; off >>= 1) {
        p1 += __shfl_xor(p1, off);
        p2 += __shfl_xor(p2, off);
    }
    if (lane == 0) { s_i[row] = p1; s_j[row] = p2; }
}

// ---------------------------------------------------------------------------
// K2 (fused att + out), 4 rows per block, 512 blocks.
//   Per row r: contiguous edge loads (lane l reads 16B at byte l*16 of a 1KB
//   window = 4 consecutive j rows), partials to part[j][col] (pad 17), sync,
//   leaky-relu + adj mask + softmax, att row -> attL[r].
//   Phase B: stream h[b] ONCE for all 4 rows (4x less L2 traffic); wave wv
//   owns k in [wv*128,+128); ds_read_b128 broadcast of attL; cross-wave
//   reduction through part[] scratch; fused elu.
// ---------------------------------------------------------------------------
__global__ __launch_bounds__(256) void k_att_out(const float* __restrict__ edge,
                                                 const float* __restrict__ adj,
                                                 const float* __restrict__ s_i,
                                                 const float* __restrict__ s_j,
                                                 const float* __restrict__ w1a3,
                                                 const float* __restrict__ h,
                                                 float* __restrict__ out) {
    int bi0 = blockIdx.x * 4;       // first of 4 rows; same b for all 4
    int b = bi0 >> 9;
    int tid = threadIdx.x;
    int wv = tid >> 6, lane = tid & 63;

    __shared__ __align__(16) float part[N][17];   // 34816 B (+ phase-B scratch)
    __shared__ __align__(16) float attL[4][N];    // 8 KB
    __shared__ float sjs[N];
    __shared__ float adjs[N];
    __shared__ __align__(16) float w1a3s[E_F];
    __shared__ float redm[4], reds[4];

    if (tid < E_F) w1a3s[tid] = w1a3[tid];
    sjs[tid]        = s_j[b * N + tid];
    sjs[tid + 256]  = s_j[b * N + tid + 256];
    float si0 = s_i[bi0], si1 = s_i[bi0 + 1], si2 = s_i[bi0 + 2], si3 = s_i[bi0 + 3];
    __syncthreads();

    int col = lane & 15;            // e-slice (4 floats)
    int jg  = lane >> 4;            // 0..3 within 4-j group
    float4 w4 = *(const float4*)&w1a3s[col * 4];

    #pragma unroll
    for (int r = 0; r < 4; ++r) {
        int bi = bi0 + r;
        float si = (r == 0) ? si0 : (r == 1) ? si1 : (r == 2) ? si2 : si3;
        adjs[tid]       = adj[(size_t)bi * N + tid];
        adjs[tid + 256] = adj[(size_t)bi * N + tid + 256];

        const float* ebase = edge + (size_t)bi * N * E_F;
        #pragma unroll
        for (int it = 0; it < 8; ++it) {
            int jw = it * 64 + wv * 16;
            #pragma unroll
            for (int i = 0; i < 4; ++i) {
                int j = jw + i * 4 + jg;
                float4 ev = *(const float4*)(ebase + (size_t)j * E_F + col * 4);
                part[j][col] = ev.x * w4.x + ev.y * w4.y + ev.z * w4.z + ev.w * w4.w;
            }
        }
        __syncthreads();

        float v0 = si + sjs[tid];
        float v1 = si + sjs[tid + 256];
        #pragma unroll
        for (int c = 0; c < 16; ++c) {
            v0 += part[tid][c];
            v1 += part[tid + 256][c];
        }
        v0 = v0 > 0.f ? v0 : ALPHA * v0;
        v1 = v1 > 0.f ? v1 : ALPHA * v1;
        v0 = (adjs[tid] > 0.f) ? v0 : NEG_INF;
        v1 = (adjs[tid + 256] > 0.f) ? v1 : NEG_INF;

        float m = fmaxf(v0, v1);
        #pragma unroll
        for (int off = 32; off; off >>= 1) m = fmaxf(m, __shfl_xor(m, off));
        if (lane == 0) redm[wv] = m;
        __syncthreads();
        m = fmaxf(fmaxf(redm[0], redm[1]), fmaxf(redm[2], redm[3]));

        float e0 = __expf(v0 - m);
        float e1 = __expf(v1 - m);
        float s = e0 + e1;
        #pragma unroll
        for (int off = 32; off; off >>= 1) s += __shfl_xor(s, off);
        if (lane == 0) reds[wv] = s;
        __syncthreads();
        s = reds[0] + reds[1] + reds[2] + reds[3];
        float inv = 1.f / s;

        attL[r][tid]       = e0 * inv;
        attL[r][tid + 256] = e1 * inv;
        __syncthreads();     // attL done; part/adjs free for next row / phase B
    }

    // Phase B: out[bi0+r][:] = elu(attL[r] @ h[b]), h streamed once.
    const float* hb = h + (size_t)b * N * OUT_F;
    int c4 = lane * 4;
    float4 ac0 = {0,0,0,0}, ac1 = {0,0,0,0}, ac2 = {0,0,0,0}, ac3 = {0,0,0,0};
    int k0 = wv * 128;
    for (int k = k0; k < k0 + 128; k += 4) {
        float4 a0 = *(const float4*)&attL[0][k];
        float4 a1 = *(const float4*)&attL[1][k];
        float4 a2 = *(const float4*)&attL[2][k];
        float4 a3 = *(const float4*)&attL[3][k];
        #pragma unroll
        for (int q = 0; q < 4; ++q) {
            float4 hv = *(const float4*)&hb[(size_t)(k + q) * OUT_F + c4];
            float f0 = q == 0 ? a0.x : q == 1 ? a0.y : q == 2 ? a0.z : a0.w;
            float f1 = q == 0 ? a1.x : q == 1 ? a1.y : q == 2 ? a1.z : a1.w;
            float f2 = q == 0 ? a2.x : q == 1 ? a2.y : q == 2 ? a2.z : a2.w;
            float f3 = q == 0 ? a3.x : q == 1 ? a3.y : q == 2 ? a3.z : a3.w;
            ac0.x = fmaf(f0, hv.x, ac0.x); ac0.y = fmaf(f0, hv.y, ac0.y);
            ac0.z = fmaf(f0, hv.z, ac0.z); ac0.w = fmaf(f0, hv.w, ac0.w);
            ac1.x = fmaf(f1, hv.x, ac1.x); ac1.y = fmaf(f1, hv.y, ac1.y);
            ac1.z = fmaf(f1, hv.z, ac1.z); ac1.w = fmaf(f1, hv.w, ac1.w);
            ac2.x = fmaf(f2, hv.x, ac2.x); ac2.y = fmaf(f2, hv.y, ac2.y);
            ac2.z = fmaf(f2, hv.z, ac2.z); ac2.w = fmaf(f2, hv.w, ac2.w);
            ac3.x = fmaf(f3, hv.x, ac3.x); ac3.y = fmaf(f3, hv.y, ac3.y);
            ac3.z = fmaf(f3, hv.z, ac3.z); ac3.w = fmaf(f3, hv.w, ac3.w);
        }
    }
    float* flat = &part[0][0];      // scratch: [wv][r][256] = 4096 floats
    *(float4*)(flat + wv * 1024 +   0 + c4) = ac0;
    *(float4*)(flat + wv * 1024 + 256 + c4) = ac1;
    *(float4*)(flat + wv * 1024 + 512 + c4) = ac2;
    *(float4*)(flat + wv * 1024 + 768 + c4) = ac3;
    __syncthreads();
    #pragma unroll
    for (int r = 0; r < 4; ++r) {
        float v = flat[r * 256 + tid] + flat[1024 + r * 256 + tid]
                + flat[2048 + r * 256 + tid] + flat[3072 + r * 256 + tid];
        out[(size_t)(bi0 + r) * OUT_F + tid] = v > 0.f ? v : (expf(v) - 1.f);
    }
}

// ---------------------------------------------------------------------------
extern "C" void kernel_launch(void* const* d_in, const int* in_sizes, int n_in,
                              void* d_out, int out_size, void* d_ws, size_t ws_size,
                              hipStream_t stream) {
    const float* x    = (const float*)d_in[0];   // (4,512,256)
    const float* edge = (const float*)d_in[1];   // (4,512,512,64)
    const float* adj  = (const float*)d_in[2];   // (4,512,512)
    const float* W    = (const float*)d_in[3];   // (256,256)
    const float* W1   = (const float*)d_in[4];   // (64,256)
    const float* a    = (const float*)d_in[5];   // (768,1)
    float* out = (float*)d_out;                  // (4,512,256)

    float* ws = (float*)d_ws;
    float* h_buf    = ws;                              // 524288 floats
    float* si_buf   = h_buf + (size_t)B * N * OUT_F;   // 2048
    float* sj_buf   = si_buf + B * N;                  // 2048
    float* w1a3_buf = sj_buf + B * N;                  // 64

    k_h<<<(B * N) / 4 + 1, 256, 0, stream>>>(x, W, W1, a, h_buf, si_buf, sj_buf, w1a3_buf);
    k_att_out<<<(B * N) / 4, 256, 0, stream>>>(edge, adj, si_buf, sj_buf, w1a3_buf, h_buf, out);
}